// Round 1
// baseline (174.367 us; speedup 1.0000x reference)
//
#include <hip/hip_runtime.h>

#define DIOU_EPS 1e-7f

__global__ void zero_out_kernel(float* out) {
    out[0] = 0.0f;
}

__global__ __launch_bounds__(256) void diou_loss_kernel(
    const float4* __restrict__ boxes1,
    const float4* __restrict__ boxes2,
    const int* __restrict__ mask,
    const int* __restrict__ num_boxes,
    float* __restrict__ out,
    int n)
{
    int tid = blockIdx.x * blockDim.x + threadIdx.x;
    int stride = gridDim.x * blockDim.x;

    float acc = 0.0f;
    for (int i = tid; i < n; i += stride) {
        float4 a = boxes1[i];   // xyxy
        float4 b = boxes2[i];
        float m = (float)(mask[i] != 0);

        // areas
        float a1 = (a.z - a.x) * (a.w - a.y);
        float a2 = (b.z - b.x) * (b.w - b.y);

        // intersection
        float ltx = fmaxf(a.x, b.x);
        float lty = fmaxf(a.y, b.y);
        float rbx = fminf(a.z, b.z);
        float rby = fminf(a.w, b.w);
        float iw = fmaxf(rbx - ltx, 0.0f);
        float ih = fmaxf(rby - lty, 0.0f);
        float inter = iw * ih;
        float uni = a1 + a2 - inter;
        float iou = inter / uni;

        // enclosing box
        float ex0 = fminf(a.x, b.x);
        float ey0 = fminf(a.y, b.y);
        float ex1 = fmaxf(a.z, b.z);
        float ey1 = fmaxf(a.w, b.w);
        float wc = ex1 - ex0;
        float hc = ey1 - ey0;
        float area_c = wc * hc;

        float giou = iou - (area_c - uni) / area_c;

        // center distance / diagonal
        float c1x = (a.x + a.z) * 0.5f;
        float c1y = (a.y + a.w) * 0.5f;
        float c2x = (b.x + b.z) * 0.5f;
        float c2y = (b.y + b.w) * 0.5f;
        float dx = c1x - c2x;
        float dy = c1y - c2y;
        float d2 = dx * dx + dy * dy;
        float diag2 = wc * wc + hc * hc;

        float diou = giou - d2 / (diag2 + DIOU_EPS);
        acc += m * (1.0f - diou);
    }

    // wave-64 butterfly reduce
    #pragma unroll
    for (int off = 32; off > 0; off >>= 1)
        acc += __shfl_down(acc, off, 64);

    __shared__ float wave_sums[4];   // 256 threads = 4 waves
    int wave = threadIdx.x >> 6;
    if ((threadIdx.x & 63) == 0) wave_sums[wave] = acc;
    __syncthreads();

    if (threadIdx.x == 0) {
        float s = wave_sums[0] + wave_sums[1] + wave_sums[2] + wave_sums[3];
        float inv_nb = 1.0f / (float)num_boxes[0];
        atomicAdd(out, s * inv_nb);
    }
}

extern "C" void kernel_launch(void* const* d_in, const int* in_sizes, int n_in,
                              void* d_out, int out_size, void* d_ws, size_t ws_size,
                              hipStream_t stream) {
    const float4* boxes1 = (const float4*)d_in[0];   // (B,Q,4) f32
    const float4* boxes2 = (const float4*)d_in[1];   // (B,Q,4) f32
    const int* mask = (const int*)d_in[2];           // (B,Q) bool -> int
    const int* num_boxes = (const int*)d_in[3];      // scalar

    float* out = (float*)d_out;
    int n = in_sizes[2];                             // B*Q pairs

    zero_out_kernel<<<1, 1, 0, stream>>>(out);

    const int block = 256;
    const int grid = 2048;                           // grid-stride, ~8 elems/thread
    diou_loss_kernel<<<grid, block, 0, stream>>>(boxes1, boxes2, mask, num_boxes, out, n);
}